// Round 6
// baseline (2009.230 us; speedup 1.0000x reference)
//
#include <hip/hip_runtime.h>

#define B_   8
#define N_   8192
#define CIN  64
#define COUT 128
#define M_   2048
#define K_   16

typedef float v2f __attribute__((ext_vector_type(2)));

// ---------------------------------------------------------------------------
// DPP wave-64 reduce helpers (VALU-only, no LDS latency).
// ---------------------------------------------------------------------------
template <int CTRL>
__device__ __forceinline__ unsigned long long dpp64(unsigned long long x) {
  int lo = (int)(unsigned)(x & 0xFFFFFFFFull);
  int hi = (int)(unsigned)(x >> 32);
  int dlo = __builtin_amdgcn_update_dpp(lo, lo, CTRL, 0xF, 0xF, false);
  int dhi = __builtin_amdgcn_update_dpp(hi, hi, CTRL, 0xF, 0xF, false);
  return ((unsigned long long)(unsigned)dhi << 32) | (unsigned)dlo;
}

__device__ __forceinline__ unsigned long long readlane_u64(unsigned long long k, int l) {
  unsigned lo = (unsigned)__builtin_amdgcn_readlane((int)(unsigned)(k & 0xFFFFFFFFull), l);
  unsigned hi = (unsigned)__builtin_amdgcn_readlane((int)(unsigned)(k >> 32), l);
  return ((unsigned long long)hi << 32) | lo;
}

__device__ __forceinline__ unsigned long long wave_min_u64(unsigned long long k) {
  unsigned long long t;
  t = dpp64<0x111>(k); k = t < k ? t : k;
  t = dpp64<0x112>(k); k = t < k ? t : k;
  t = dpp64<0x114>(k); k = t < k ? t : k;
  t = dpp64<0x118>(k); k = t < k ? t : k;
  t = dpp64<0x142>(k); k = t < k ? t : k;
  t = dpp64<0x143>(k); k = t < k ? t : k;
  return readlane_u64(k, 63);
}

// single-value DPP ladder steps (foldable to v_max_f32_dpp / v_max_u32_dpp)
template <int CTRL>
__device__ __forceinline__ float dppmaxf(float x) {
  int t = __builtin_amdgcn_update_dpp(__float_as_int(x), __float_as_int(x),
                                      CTRL, 0xF, 0xF, false);
  return fmaxf(__int_as_float(t), x);
}
template <int CTRL>
__device__ __forceinline__ unsigned dppmaxu(unsigned x) {
  unsigned t = (unsigned)__builtin_amdgcn_update_dpp((int)x, (int)x,
                                                     CTRL, 0xF, 0xF, false);
  return t > x ? t : x;
}

// ---------------------------------------------------------------------------
// 1+2) Merged FPS + MLP kernel (R13 structure, verified at 1988 us total).
//      Blocks 0..7: FPS (one per batch), 4 waves x 32 pts/lane = 1 wave/SIMD.
//      Blocks 8..4103: MLP tiles (16 rows each, 256 threads).
//
//      R17 change (FPS only): within-wave argmax reduce is SPLIT —
//      6-stage f32 DPP max ladder on bd (positive floats order as uints),
//      readlane(63) broadcast, then 6-stage u32 DPP max over
//      (bd==wmax ? N-1-n : 0). Exactly the old u64 (d<<32 | N-1-n) max:
//      primary max d-bits, ties -> max N-1-n = min n; non-tie lanes give 0
//      which never beats a tie lane (if winner lo==0 then winner IS n=8191
//      and all lanes agree). Lane 63 re-packs the identical u64 key into
//      wred, so cross-wave decode is VERBATIM R13.
//
//      FPS distance numerics: f32 strict numpy order ((dx^2+dy^2)+dz^2)
//      NO-FMA (contract off; pk ops elementwise IEEE identical),
//      elementwise min. MLP numerics bit-identical (ascending c4,
//      xv.x*w0 + xv.y*w1 + xv.z*w2 + xv.w*w3).
// ---------------------------------------------------------------------------
#define FTH 256
#define FPT 32    // points per thread = N_/FTH
#define MROWS2 16 // rows per mlp block (256 threads)

__global__ __launch_bounds__(256) void fps_mlp_kernel(
    const float* __restrict__ p, float* __restrict__ p_out,
    const float* __restrict__ x, const float* __restrict__ W,
    const float* __restrict__ gamma, const float* __restrict__ beta,
    const float* __restrict__ rmean, const float* __restrict__ rvar,
    float* __restrict__ h) {
#pragma clang fp contract(off)
  __shared__ __align__(16) unsigned char smem[139776];

  const int tid = threadIdx.x;

  if (blockIdx.x >= 8) {
    // ---------------- MLP tile ----------------
    float* wt = (float*)smem;                   // W^T padded: wt[c*132+o]
    float* xs = (float*)(smem + 33792);         // xs[r*64+c], 16 rows

    const int o  = tid & 127;
    const int rg = tid >> 7;                    // 0..1 -> rows rg*8..rg*8+7
    const int rowBase = (blockIdx.x - 8) * MROWS2;

    for (int idx = tid; idx < COUT * CIN; idx += 256) {
      const int oo = idx >> 6, cc = idx & 63;
      wt[cc * 132 + oo] = W[idx];
    }
    ((float4*)xs)[tid] = ((const float4*)(x + (size_t)rowBase * CIN))[tid];
    __syncthreads();

    float acc[8] = {0.f, 0.f, 0.f, 0.f, 0.f, 0.f, 0.f, 0.f};
#pragma unroll
    for (int c4 = 0; c4 < CIN / 4; c4++) {
      const float w0 = wt[(4 * c4 + 0) * 132 + o];
      const float w1 = wt[(4 * c4 + 1) * 132 + o];
      const float w2 = wt[(4 * c4 + 2) * 132 + o];
      const float w3 = wt[(4 * c4 + 3) * 132 + o];
#pragma unroll
      for (int i = 0; i < 8; i++) {
        const float4 xv = *(const float4*)&xs[(rg * 8 + i) * CIN + c4 * 4];
        acc[i] += xv.x * w0 + xv.y * w1 + xv.z * w2 + xv.w * w3;
      }
    }
    const float mu = rmean[o];
    const float sc = rsqrtf(rvar[o] + 1e-5f) * gamma[o];
    const float bt = beta[o];
#pragma unroll
    for (int i = 0; i < 8; i++) {
      const float v = (acc[i] - mu) * sc + bt;
      h[(size_t)(rowBase + rg * 8 + i) * COUT + o] = fmaxf(v, 0.f);
    }
    return;
  }

  // ---------------- FPS ----------------
  float4* pc4 = (float4*)smem;                               // 128 KB
  unsigned long long (*wred)[8] =
      (unsigned long long (*)[8])(smem + 131072);            // 2*8*8 B
  int* idxHist = (int*)(smem + 131072 + 128);                // 8 KB

  const int b  = blockIdx.x;
  const int wv = tid >> 6;                                   // 0..3
  const int ln = tid & 63;

  const float* pb = p + (size_t)b * N_ * 3;
  for (int n = tid; n < N_; n += FTH)
    pc4[n] = make_float4(pb[3 * n + 0], pb[3 * n + 1], pb[3 * n + 2], 0.f);
  if (tid == 0) idxHist[0] = 0;
  __syncthreads();

  float4 c0 = pc4[0];
  float cx = c0.x, cy = c0.y, cz = c0.z;

  // pairs: element e of pair j is point n = tid + (2j+e)*256, slot s = 2j+e
  v2f X2[16], Y2[16], Z2[16], D2[16];
#pragma unroll
  for (int j = 0; j < 16; j++) {
    float4 a = pc4[tid + (2 * j) * FTH];
    float4 c = pc4[tid + (2 * j + 1) * FTH];
    X2[j] = (v2f){a.x, c.x};
    Y2[j] = (v2f){a.y, c.y};
    Z2[j] = (v2f){a.z, c.z};
    D2[j] = (v2f){__builtin_inff(), __builtin_inff()};
  }

  int buf = 0;
  for (int it = 1; it < M_; ++it) {
    const v2f cxv = {cx, cx}, cyv = {cy, cy}, czv = {cz, cz};
    v2f vbd = (v2f){-1.0f, -1.0f};     // all dm >= 0 -> slot 0/1 always wins
    int sx = 0, sy = 1;                // even-chain slot, odd-chain slot
#pragma unroll
    for (int j = 0; j < 16; j++) {
      v2f dx = X2[j] - cxv;
      v2f dy = Y2[j] - cyv;
      v2f dz = Z2[j] - czv;
      v2f m1 = dx * dx;
      v2f m2 = dy * dy;
      v2f s  = m1 + m2;
      v2f m3 = dz * dz;
      v2f d  = s + m3;                           // numpy order, no fma
      v2f dm = __builtin_elementwise_min(D2[j], d);
      D2[j] = dm;
      const bool gx = dm.x > vbd.x;              // strict > keeps first max
      const bool gy = dm.y > vbd.y;
      sx = gx ? (2 * j) : sx;
      sy = gy ? (2 * j + 1) : sy;
      vbd = __builtin_elementwise_max(vbd, dm);
    }
    // combine even/odd chains: larger d, tie -> smaller slot (= smaller n)
    float bd; int bk;
    if (vbd.y > vbd.x || (vbd.y == vbd.x && sy < sx)) { bd = vbd.y; bk = sy; }
    else                                               { bd = vbd.x; bk = sx; }
    const int n = tid + (bk << 8);

    // ---- split within-wave argmax reduce (R17) ----
    // (a) wave max of bd: 6-stage f32 DPP ladder (full max lands in lane 63)
    float wm = bd;
    wm = dppmaxf<0x111>(wm);                    // row_shr:1
    wm = dppmaxf<0x112>(wm);                    // row_shr:2
    wm = dppmaxf<0x114>(wm);                    // row_shr:4
    wm = dppmaxf<0x118>(wm);                    // row_shr:8
    wm = dppmaxf<0x142>(wm);                    // row_bcast:15
    wm = dppmaxf<0x143>(wm);                    // row_bcast:31
    const unsigned wmax_bits =
        (unsigned)__builtin_amdgcn_readlane(__float_as_int(wm), 63);
    // (b) among bitwise-tie lanes, max (N-1-n) = min n; others give 0
    unsigned lo = (__float_as_uint(bd) == wmax_bits)
                      ? (unsigned)(N_ - 1 - n) : 0u;
    lo = dppmaxu<0x111>(lo);
    lo = dppmaxu<0x112>(lo);
    lo = dppmaxu<0x114>(lo);
    lo = dppmaxu<0x118>(lo);
    lo = dppmaxu<0x142>(lo);
    lo = dppmaxu<0x143>(lo);
    if (ln == 63)                                // identical u64 key as before
      wred[buf][wv] = ((unsigned long long)wmax_bits << 32) | lo;
    __syncthreads();                             // the ONLY barrier per iter
    // lane-parallel decode: lanes load the 4 wave keys, 2-stage DPP max,
    // read back only the low dword (n is all we need). VERBATIM R13.
    unsigned long long kk = wred[buf][ln & 3];
    unsigned long long t;
    t = dpp64<0x111>(kk); kk = t > kk ? t : kk;
    t = dpp64<0x112>(kk); kk = t > kk ? t : kk;
    const int nw = N_ - 1 -
        (int)(unsigned)__builtin_amdgcn_readlane((int)(unsigned)(kk & 0xFFFFFFFFull), 3);
    float4 cc = pc4[nw];                        // 1 broadcast b128
    cx = cc.x; cy = cc.y; cz = cc.z;
    if (tid == 0) idxHist[it] = nw;
    buf ^= 1;
  }
  __syncthreads();

  float* po = p_out + (size_t)b * M_ * 3;
  for (int mi = tid; mi < M_; mi += FTH) {
    float4 v = pc4[idxHist[mi]];
    po[mi * 3 + 0] = v.x;
    po[mi * 3 + 1] = v.y;
    po[mi * 3 + 2] = v.z;
  }
}

// ---------------------------------------------------------------------------
// 3) KNN — VERBATIM from the passing chain. 16 queries/block, p[b]+sn staged
//    in LDS once per block; per-lane sorted top-4 cache, 16 DPP-min rounds,
//    exact rescan; fused gather/max-pool. d2 bits identical.
// ---------------------------------------------------------------------------
#define UMAXK 0xFFFFFFFFFFFFFFFFull
#define QPB  16   // queries (waves) per block

__global__ __launch_bounds__(1024) void knn_kernel(
    const float* __restrict__ p, const float* __restrict__ p_out,
    const float* __restrict__ h, float* __restrict__ y) {
#pragma clang fp contract(off)
  __shared__ float4 pc4[N_];            // 128 KB: x,y,z,sn
  __shared__ int winLds[QPB][K_];

  const int t    = threadIdx.x;
  const int wv   = t >> 6;
  const int lane = t & 63;
  const int b    = blockIdx.x & 7;      // batch: keeps h[b] on one XCD (heur.)
  const int grp  = blockIdx.x >> 3;     // 0..127
  const int q    = b * M_ + grp * QPB + wv;

  const float* pb = p + (size_t)b * N_ * 3;
  for (int n = t; n < N_; n += 1024) {
    float xx = pb[3 * n + 0], yy = pb[3 * n + 1], zz = pb[3 * n + 2];
    float sn = (xx * xx + yy * yy) + zz * zz;   // numpy sum, no fma
    pc4[n] = make_float4(xx, yy, zz, sn);
  }
  __syncthreads();

  const float qx = p_out[q * 3 + 0];
  const float qy = p_out[q * 3 + 1];
  const float qz = p_out[q * 3 + 2];
  const float sq = (qx * qx + qy * qy) + qz * qz;   // numpy sum, no fma

  unsigned long long c0 = UMAXK, c1 = UMAXK, c2 = UMAXK, c3 = UMAXK;
#pragma unroll 4
  for (int j = 0; j < 128; j++) {
    const int n = lane + (j << 6);
    float4 v = pc4[n];
    float dot = __builtin_fmaf(qz, v.z,
                __builtin_fmaf(qy, v.y, qx * v.x)); // BLAS fma chain, k asc
    float d2 = (sq + v.w) - 2.0f * dot;
    unsigned u = __float_as_uint(d2);
    u ^= (unsigned)((int)u >> 31) | 0x80000000u;    // monotone f32->u32
    unsigned long long key = ((unsigned long long)u << 32) | (unsigned)n;
    if (key < c3) {
      unsigned long long x2 = key, mn;
      mn = x2 < c0 ? x2 : c0; x2 = x2 < c0 ? c0 : x2; c0 = mn;
      mn = x2 < c1 ? x2 : c1; x2 = x2 < c1 ? c1 : x2; c1 = mn;
      mn = x2 < c2 ? x2 : c2; x2 = x2 < c2 ? c2 : x2; c2 = mn;
      c3 = x2 < c3 ? x2 : c3;
    }
  }

  int count = 4;
  unsigned long long em0 = 0ull, em1 = 0ull;    // extraction mask (128 bits)
  unsigned long long mykey = UMAXK;             // lane r keeps round-r winner

  for (int k = 0; k < K_; k++) {
    unsigned long long cnd = (count > 0) ? c0 : UMAXK;
    unsigned long long win = wave_min_u64(cnd); // uniform; unique n => exact
    if (lane == k) mykey = win;
    const int nstar = (int)(unsigned)(win & 0xFFFFFFFFu);
    if ((nstar & 63) == lane) {                 // I own the winner (== my c0)
      const int j = nstar >> 6;
      if (j < 64) em0 |= 1ull << j; else em1 |= 1ull << (j - 64);
      c0 = c1; c1 = c2; c2 = c3; c3 = UMAXK; count--;
      if (count == 0 && k < K_ - 1) {           // rare exact rescan from LDS
        c0 = c1 = c2 = c3 = UMAXK;
        for (int j2 = 0; j2 < 128; j2++) {
          bool ex = (j2 < 64) ? ((em0 >> j2) & 1ull) : ((em1 >> (j2 - 64)) & 1ull);
          if (!ex) {
            const int n2 = lane + (j2 << 6);
            float4 v = pc4[n2];
            float dot = __builtin_fmaf(qz, v.z,
                        __builtin_fmaf(qy, v.y, qx * v.x));
            float d2 = (sq + v.w) - 2.0f * dot;
            unsigned u = __float_as_uint(d2);
            u ^= (unsigned)((int)u >> 31) | 0x80000000u;
            unsigned long long kk2 = ((unsigned long long)u << 32) | (unsigned)n2;
            if (kk2 < c3) {
              unsigned long long x2 = kk2, mn;
              mn = x2 < c0 ? x2 : c0; x2 = x2 < c0 ? c0 : x2; c0 = mn;
              mn = x2 < c1 ? x2 : c1; x2 = x2 < c1 ? c1 : x2; c1 = mn;
              mn = x2 < c2 ? x2 : c2; x2 = x2 < c2 ? c2 : x2; c2 = mn;
              c3 = x2 < c3 ? x2 : c3;
            }
          }
        }
        count = 4;
      }
    }
  }

  if (lane < K_) winLds[wv][lane] = (int)(unsigned)(mykey & 0xFFFFFFFFu);
  __syncthreads();

  const float* hb = h + (size_t)b * N_ * COUT;
  float2 acc = make_float2(-__builtin_inff(), -__builtin_inff());
#pragma unroll
  for (int i = 0; i < K_; i++) {
    const int n = winLds[wv][i];                // LDS broadcast read
    float2 v = *(const float2*)(hb + (size_t)n * COUT + lane * 2);
    acc.x = fmaxf(acc.x, v.x);
    acc.y = fmaxf(acc.y, v.y);
  }
  *(float2*)(y + (size_t)q * COUT + lane * 2) = acc;
}

// ---------------------------------------------------------------------------
extern "C" void kernel_launch(void* const* d_in, const int* in_sizes, int n_in,
                              void* d_out, int out_size, void* d_ws, size_t ws_size,
                              hipStream_t stream) {
  const float* x     = (const float*)d_in[0];
  const float* p     = (const float*)d_in[1];
  const float* W     = (const float*)d_in[2];
  const float* gamma = (const float*)d_in[3];
  const float* beta  = (const float*)d_in[4];
  const float* rmean = (const float*)d_in[5];
  const float* rvar  = (const float*)d_in[6];

  float* y     = (float*)d_out;                       // (B, M, COUT)
  float* p_out = y + (size_t)B_ * M_ * COUT;          // (B, M, 3)
  float* h     = (float*)d_ws;                        // (B, N, COUT) scratch

  fps_mlp_kernel<<<8 + (B_ * N_) / MROWS2, 256, 0, stream>>>(
      p, p_out, x, W, gamma, beta, rmean, rvar, h);
  knn_kernel<<<B_ * (M_ / QPB), 1024, 0, stream>>>(p, p_out, h, y);
}